// Round 9
// baseline (225.630 us; speedup 1.0000x reference)
//
#include <hip/hip_runtime.h>
#include <hip/hip_bf16.h>

// Problem constants (B=2, P=2048, D=768, H=12, hd=64)
#define B_  2
#define P_  2048
#define D_  768
#define H_  12
#define HD_ 64
#define M_  (B_ * P_)   // 4096
#define N1_ (3 * D_)    // 2304

typedef __attribute__((ext_vector_type(8))) short short8;    // 8 bf16 (4 VGPRs)
typedef __attribute__((ext_vector_type(4))) float f32x4;     // 16x16 MFMA acc
typedef __attribute__((ext_vector_type(16))) float f32x16;   // 32x32 MFMA acc
typedef __attribute__((ext_vector_type(4))) unsigned u32x4;
typedef unsigned short ushort;

__device__ __forceinline__ ushort f2bf(float f) {
    unsigned u = __float_as_uint(f);
    u += 0x7fffu + ((u >> 16) & 1u);   // RNE
    return (ushort)(u >> 16);
}

// Pack 2 floats -> 1 dword of 2x bf16 (lo=a, hi=b), RNE. HW-verified (r5/r6).
__device__ __forceinline__ unsigned cvtpk(float a, float b) {
    unsigned r;
    asm("v_cvt_pk_bf16_f32 %0, %1, %2" : "=v"(r) : "v"(a), "v"(b));
    return r;
}

__device__ __forceinline__ float bf2f(ushort u) {
    return __uint_as_float((unsigned)u << 16);
}

// Swap bits 2 and 3 of a slot index (involution) — attn K staging permutation.
__device__ __forceinline__ int swap23(int s) {
    return (s & ~12) | ((s & 4) << 1) | ((s & 8) >> 1);
}

// Q pre-scale: hd^-0.5 * log2(e) — attn uses exp2 directly.
#define QSC_ (0.125f * 1.44269504088896340736f)

// ===========================================================================
// Kernel 1 (R9 rewrite): qkv = x @ W_qkv + fused per-head QK-LayerNorm.
// 128x64 tile, BK=64, 256 threads / 4 waves; wave owns 32 rows x 64 cols.
// A (x rows) loaded DIRECT from global per-wave (each row used by exactly one
// wave — LDS staging shared nothing). B double-buffered in LDS, one barrier
// per K-step (12 steps). Each block covers exactly one head (64 cols).
// Grid 1152 (vs 576): XCD-swizzled so the 4 row-slabs per XCD stay L2-hot.
// ===========================================================================
__global__ __launch_bounds__(256) void gemm_qkv_mfma(
        const float* __restrict__ x, const float* __restrict__ w,
        const float* __restrict__ qs, const float* __restrict__ qb,
        const float* __restrict__ ks, const float* __restrict__ kb,
        ushort* __restrict__ qkv) {
    __shared__ __align__(16) ushort Bs[2][64][72];

    // Bijective XCD decode: nwg=1152=8*144; by%8 == L%8 (assumed xcd=L%8).
    const int L   = blockIdx.x;
    const int xcd = L & 7;
    const int idx = L >> 3;              // 0..143
    const int by  = xcd + 8 * (idx / 36);   // 0..31
    const int bx  = idx % 36;
    const int rowBase = by * 128;
    const int colBase = bx * 64;

    const int tid  = threadIdx.x;
    const int lane = tid & 63;
    const int wv   = tid >> 6;           // 0..3
    const int quad = lane >> 4;
    const int col  = lane & 15;

    // B staging: n = tid&63, k-group kg = tid>>6 (16 k-rows each).
    const int nB = tid & 63, kg = tid >> 6;

    float bpre[16];
    auto load_b = [&](int kt) {
        const int k0 = kt * 64;
#pragma unroll
        for (int j = 0; j < 16; j++)
            bpre[j] = w[(size_t)(k0 + kg * 16 + j) * N1_ + colBase + nB];
    };
    auto stage_b = [&](int buf) {
        u32x4 b0, b1;
#pragma unroll
        for (int j = 0; j < 4; j++) b0[j] = cvtpk(bpre[2 * j], bpre[2 * j + 1]);
#pragma unroll
        for (int j = 0; j < 4; j++) b1[j] = cvtpk(bpre[8 + 2 * j], bpre[8 + 2 * j + 1]);
        *(u32x4*)&Bs[buf][nB][kg * 16]     = b0;
        *(u32x4*)&Bs[buf][nB][kg * 16 + 8] = b1;
    };

    // A direct: wave-private rows. Frag (mt,k32): lane reads 8 floats at
    // x[row = rowBase + wv*32 + mt*16 + col][k0 + k32*32 + quad*8 .. +7].
    const float* arow0 = x + (size_t)(rowBase + wv * 32 + col) * D_ + quad * 8;
    const float* arow1 = arow0 + (size_t)16 * D_;
    float4 apre[2][2][2];                // [mt][k32][half]
    auto load_a = [&](int kt) {
        const int k0 = kt * 64;
#pragma unroll
        for (int k32 = 0; k32 < 2; k32++) {
            apre[0][k32][0] = *(const float4*)(arow0 + k0 + k32 * 32);
            apre[0][k32][1] = *(const float4*)(arow0 + k0 + k32 * 32 + 4);
            apre[1][k32][0] = *(const float4*)(arow1 + k0 + k32 * 32);
            apre[1][k32][1] = *(const float4*)(arow1 + k0 + k32 * 32 + 4);
        }
    };

    f32x4 acc[2][4];
#pragma unroll
    for (int i = 0; i < 2; i++)
#pragma unroll
        for (int j = 0; j < 4; j++) acc[i][j] = (f32x4){0.f, 0.f, 0.f, 0.f};

    load_a(0);
    load_b(0);
    stage_b(0);
    __syncthreads();

    const int NT = D_ / 64;              // 12
    int cur = 0;
    for (int kt = 0; kt < NT; kt++) {
        const bool more = (kt + 1 < NT);

        short8 af[2][2];
#pragma unroll
        for (int mt = 0; mt < 2; mt++)
#pragma unroll
            for (int k32 = 0; k32 < 2; k32++) {
                u32x4 t;
                t[0] = cvtpk(apre[mt][k32][0].x, apre[mt][k32][0].y);
                t[1] = cvtpk(apre[mt][k32][0].z, apre[mt][k32][0].w);
                t[2] = cvtpk(apre[mt][k32][1].x, apre[mt][k32][1].y);
                t[3] = cvtpk(apre[mt][k32][1].z, apre[mt][k32][1].w);
                af[mt][k32] = __builtin_bit_cast(short8, t);
            }

        if (more) { load_a(kt + 1); load_b(kt + 1); }

#pragma unroll
        for (int k32 = 0; k32 < 2; k32++) {
            short8 bf[4];
#pragma unroll
            for (int nt = 0; nt < 4; nt++)
                bf[nt] = *(const short8*)&Bs[cur][nt * 16 + col][k32 * 32 + quad * 8];
#pragma unroll
            for (int mt = 0; mt < 2; mt++)
#pragma unroll
                for (int nt = 0; nt < 4; nt++)
                    acc[mt][nt] = __builtin_amdgcn_mfma_f32_16x16x32_bf16(af[mt][k32], bf[nt], acc[mt][nt], 0, 0, 0);
        }

        if (more) {
            stage_b(cur ^ 1);
            __syncthreads();
            cur ^= 1;
        }
    }

    // Epilogue: block = one head-chunk. comp 0=q,1=k,2=v; h = chunk index.
    const int comp = colBase / D_;
    const int rem  = colBase - comp * D_;
    const int h    = rem >> 6;
    float sc4[4] = {0, 0, 0, 0}, bi4[4] = {0, 0, 0, 0};
    if (comp == 0) {
#pragma unroll
        for (int nt = 0; nt < 4; nt++) { sc4[nt] = qs[nt * 16 + col]; bi4[nt] = qb[nt * 16 + col]; }
    } else if (comp == 1) {
#pragma unroll
        for (int nt = 0; nt < 4; nt++) { sc4[nt] = ks[nt * 16 + col]; bi4[nt] = kb[nt * 16 + col]; }
    }

#pragma unroll
    for (int mt = 0; mt < 2; mt++) {
#pragma unroll
        for (int r = 0; r < 4; r++) {
            int m  = rowBase + wv * 32 + mt * 16 + quad * 4 + r;
            int bb = m >> 11;
            int p  = m & 2047;
            float v0 = acc[mt][0][r], v1 = acc[mt][1][r], v2 = acc[mt][2][r], v3 = acc[mt][3][r];
            if (comp < 2) {
                float s = v0 + v1 + v2 + v3;
#pragma unroll
                for (int off = 1; off < 16; off <<= 1) s += __shfl_xor(s, off, 64);
                float mean = s * (1.0f / 64.0f);
                float d0 = v0 - mean, d1 = v1 - mean, d2 = v2 - mean, d3 = v3 - mean;
                float sq = d0 * d0 + d1 * d1 + d2 * d2 + d3 * d3;
#pragma unroll
                for (int off = 1; off < 16; off <<= 1) sq += __shfl_xor(sq, off, 64);
                float inv = rsqrtf(sq * (1.0f / 64.0f) + 1e-6f);
                v0 = d0 * inv * sc4[0] + bi4[0];
                v1 = d1 * inv * sc4[1] + bi4[1];
                v2 = d2 * inv * sc4[2] + bi4[2];
                v3 = d3 * inv * sc4[3] + bi4[3];
                if (comp == 0) { v0 *= QSC_; v1 *= QSC_; v2 *= QSC_; v3 *= QSC_; }
            }
            size_t base = ((((size_t)comp * B_ + bb) * H_ + h) * P_ + p) * HD_;
            qkv[base +  0 + col] = f2bf(v0);
            qkv[base + 16 + col] = f2bf(v1);
            qkv[base + 32 + col] = f2bf(v2);
            qkv[base + 48 + col] = f2bf(v3);
        }
    }
}

// ===========================================================================
// Kernel 2: flash attention (unchanged from R8 — swapped QK^T, swap23,
// double-buffered K/V, exp2 softmax, in-register P, bf16 partial-O).
// ===========================================================================
__global__ __launch_bounds__(256) void attn_split(const ushort* __restrict__ qkv,
                                                  ushort* __restrict__ o0, ushort* __restrict__ o1,
                                                  ushort* __restrict__ o2, ushort* __restrict__ o3,
                                                  float* __restrict__ l0, float* __restrict__ l1,
                                                  float* __restrict__ l2, float* __restrict__ l3) {
    const int p0  = blockIdx.x * 128;
    const int bh  = blockIdx.y;
    const int s   = blockIdx.z;
    const int nsp = gridDim.z;           // 2 or 4
    const int b   = bh / H_, h = bh % H_;
    ushort* opart = (s == 0) ? o0 : (s == 1) ? o1 : (s == 2) ? o2 : o3;
    float*  lpart = (s == 0) ? l0 : (s == 1) ? l1 : (s == 2) ? l2 : l3;
    const int tid  = threadIdx.x;
    const int lane = tid & 63;
    const int wv   = tid >> 6;
    const int half = lane >> 5;     // 0/1
    const int n32  = lane & 31;     // q-column of this lane

    __shared__ __align__(16) ushort KVs[2][2][64][72];

    const size_t hs  = (size_t)P_ * HD_;
    const int    kv0 = s * (P_ / nsp);
    const ushort* qg = qkv + ((size_t)(0 * B_ + b) * H_ + h) * hs + (size_t)(p0 + wv * 32) * HD_;
    const ushort* kg = qkv + ((size_t)(1 * B_ + b) * H_ + h) * hs + (size_t)kv0 * HD_;
    const ushort* vg = qkv + ((size_t)(2 * B_ + b) * H_ + h) * hs + (size_t)kv0 * HD_;

    short8 aq[4];
#pragma unroll
    for (int ks2 = 0; ks2 < 4; ks2++)
        aq[ks2] = *(const short8*)(qg + (size_t)n32 * HD_ + ks2 * 16 + half * 8);

    float lsum = 0.f;
    f32x16 oaccT[2];
#pragma unroll
    for (int nt = 0; nt < 2; nt++)
#pragma unroll
        for (int r = 0; r < 16; r++) oaccT[nt][r] = 0.f;

    const int kr = tid >> 3, kc8 = tid & 7;
    const int krs = swap23(kr);
    const int vd = tid & 63,  vkh = tid >> 6;

    uint4  kpre[2];
    ushort vpre[16];
    auto load_tile = [&](int kt) {
        const ushort* kg_t = kg + (size_t)kt * 64 * HD_;
        const ushort* vg_t = vg + (size_t)kt * 64 * HD_;
        kpre[0] = *(const uint4*)(kg_t + (size_t)kr * HD_ + kc8 * 8);
        kpre[1] = *(const uint4*)(kg_t + (size_t)(kr + 32) * HD_ + kc8 * 8);
#pragma unroll
        for (int j = 0; j < 16; j++)
            vpre[j] = vg_t[(size_t)(vkh * 16 + j) * HD_ + vd];
    };
    auto stage = [&](int buf) {
        *(uint4*)&KVs[buf][0][krs][kc8 * 8]      = kpre[0];
        *(uint4*)&KVs[buf][0][krs + 32][kc8 * 8] = kpre[1];
        *(short8*)&KVs[buf][1][vd][vkh * 16]     = *(short8*)&vpre[0];
        *(short8*)&KVs[buf][1][vd][vkh * 16 + 8] = *(short8*)&vpre[8];
    };

    load_tile(0);
    stage(0);
    __syncthreads();

    const int NT = (P_ / 64) / nsp;
    int cur = 0;
    for (int kt = 0; kt < NT; kt++) {
        const bool more = (kt + 1 < NT);
        if (more) load_tile(kt + 1);

        ushort (*Ks)[72] = KVs[cur][0];
        ushort (*Vs)[72] = KVs[cur][1];

#pragma unroll
        for (int nt = 0; nt < 2; nt++) {
            f32x16 sc;
#pragma unroll
            for (int r = 0; r < 16; r++) sc[r] = 0.f;
#pragma unroll
            for (int ks2 = 0; ks2 < 4; ks2++) {
                short8 kb2 = *(const short8*)&Ks[nt * 32 + n32][ks2 * 16 + half * 8];
                sc = __builtin_amdgcn_mfma_f32_32x32x16_bf16(kb2, aq[ks2], sc, 0, 0, 0);
            }
            float p[16];
#pragma unroll
            for (int r = 0; r < 16; r++) {
                p[r] = __builtin_amdgcn_exp2f(sc[r]);
                lsum += p[r];
            }
            unsigned w[8];
#pragma unroll
            for (int i = 0; i < 8; i++) w[i] = cvtpk(p[2 * i], p[2 * i + 1]);
#pragma unroll
            for (int kp2 = 0; kp2 < 2; kp2++) {
                u32x4 t = {w[kp2 * 4 + 0], w[kp2 * 4 + 1], w[kp2 * 4 + 2], w[kp2 * 4 + 3]};
                short8 pb = __builtin_bit_cast(short8, t);
                const int kstep = nt * 2 + kp2;
#pragma unroll
                for (int ntd = 0; ntd < 2; ntd++) {
                    short8 av = *(const short8*)&Vs[ntd * 32 + n32][kstep * 16 + half * 8];
                    oaccT[ntd] = __builtin_amdgcn_mfma_f32_32x32x16_bf16(av, pb, oaccT[ntd], 0, 0, 0);
                }
            }
        }

        if (more) {
            stage(cur ^ 1);
            __syncthreads();
            cur ^= 1;
        }
    }

    lsum += __shfl_xor(lsum, 32, 64);
    if (lane < 32)
        lpart[(size_t)bh * P_ + p0 + wv * 32 + lane] = lsum;

    float* scr = (float*)&KVs[0][0][0][0] + wv * 1152;
#pragma unroll
    for (int ntd = 0; ntd < 2; ntd++) {
#pragma unroll
        for (int r = 0; r < 16; r++)
            scr[n32 * 36 + (r & 3) + 8 * (r >> 2) + 4 * half] = oaccT[ntd][r];
#pragma unroll
        for (int i = 0; i < 4; i++) {
            int ql = i * 8 + (lane >> 3);
            int c4 = lane & 7;
            float4 v = *(const float4*)&scr[ql * 36 + c4 * 4];
            uint2 pk = {cvtpk(v.x, v.y), cvtpk(v.z, v.w)};
            *(uint2*)(opart + ((size_t)bh * P_ + p0 + wv * 32 + ql) * HD_ + ntd * 32 + c4 * 4) = pk;
        }
    }
}

// ===========================================================================
// Kernel 3: LayerNorm over D=768, fused split-combine of bf16 partials.
// (unchanged from R8)
// ===========================================================================
__global__ __launch_bounds__(256) void ln_o(const ushort* __restrict__ o0,
                                            const ushort* __restrict__ o1,
                                            const ushort* __restrict__ o2,
                                            const ushort* __restrict__ o3,
                                            const float* __restrict__ l0,
                                            const float* __restrict__ l1,
                                            const float* __restrict__ l2,
                                            const float* __restrict__ l3,
                                            const int ns,
                                            ushort* __restrict__ lnb,
                                            const float* __restrict__ osc,
                                            const float* __restrict__ ob) {
    __shared__ float red[4];
    __shared__ float red2[4];
    const int row = blockIdx.x;          // b*P + p
    const int b   = row >> 11;
    const int p   = row & (P_ - 1);
    const int tid = threadIdx.x;

    auto src = [&](int d) {
        int h = d >> 6;
        size_t lr  = (size_t)(b * H_ + h) * P_ + p;
        size_t idx = lr * HD_ + (d & 63);
        float num = bf2f(o0[idx]) + bf2f(o1[idx]);
        float den = l0[lr] + l1[lr];
        if (ns == 4) { num += bf2f(o2[idx]) + bf2f(o3[idx]); den += l2[lr] + l3[lr]; }
        return num / den;
    };
    float v0 = src(tid);
    float v1 = src(tid + 256);
    float v2 = src(tid + 512);
    float s = v0 + v1 + v2;
#pragma unroll
    for (int o = 32; o > 0; o >>= 1) s += __shfl_xor(s, o, 64);
    if ((tid & 63) == 0) red[tid >> 6] = s;
    __syncthreads();
    float mean = (red[0] + red[1] + red[2] + red[3]) * (1.0f / 768.0f);
    float d0 = v0 - mean, d1 = v1 - mean, d2 = v2 - mean;
    float sq = d0 * d0 + d1 * d1 + d2 * d2;
#pragma unroll
    for (int o = 32; o > 0; o >>= 1) sq += __shfl_xor(sq, o, 64);
    if ((tid & 63) == 0) red2[tid >> 6] = sq;
    __syncthreads();
    float var = (red2[0] + red2[1] + red2[2] + red2[3]) * (1.0f / 768.0f);
    float inv = rsqrtf(var + 1e-6f);
    const size_t base = (size_t)row * D_;
    lnb[base + tid]       = f2bf(d0 * inv * osc[tid]       + ob[tid]);
    lnb[base + tid + 256] = f2bf(d1 * inv * osc[tid + 256] + ob[tid + 256]);
    lnb[base + tid + 512] = f2bf(d2 * inv * osc[tid + 512] + ob[tid + 512]);
}

// ===========================================================================
// Kernel 4 (R9 rewrite): out = ln_buf(bf16) @ W_out + b_out.
// 64x64 tile, BK=64, 256 threads / 4 waves; wave owns 16 rows x 64 cols.
// A (bf16) direct-from-global (1 uint4 per frag); B double-buffered LDS.
// Grid 768, XCD-swizzled (by%8 clustering).
// ===========================================================================
__global__ __launch_bounds__(256) void gemm_out_mfma(
        const ushort* __restrict__ a, const float* __restrict__ w,
        const float* __restrict__ bias, float* __restrict__ out) {
    __shared__ __align__(16) ushort Bs[2][64][72];

    const int L   = blockIdx.x;
    const int xcd = L & 7;
    const int idx = L >> 3;              // 0..95
    const int by  = xcd + 8 * (idx / 12);   // 0..63
    const int bx  = idx % 12;
    const int rowBase = by * 64;
    const int colBase = bx * 64;

    const int tid  = threadIdx.x;
    const int lane = tid & 63;
    const int wv   = tid >> 6;           // 0..3
    const int quad = lane >> 4;
    const int col  = lane & 15;

    const int nB = tid & 63, kg = tid >> 6;

    float bpre[16];
    auto load_b = [&](int kt) {
        const int k0 = kt * 64;
#pragma unroll
        for (int j = 0; j < 16; j++)
            bpre[j] = w[(size_t)(k0 + kg * 16 + j) * D_ + colBase + nB];
    };
    auto stage_b = [&](int buf) {
        u32x4 b0, b1;
#pragma unroll
        for (int j = 0; j < 4; j++) b0[j] = cvtpk(bpre[2 * j], bpre[2 * j + 1]);
#pragma unroll
        for (int j = 0; j < 4; j++) b1[j] = cvtpk(bpre[8 + 2 * j], bpre[8 + 2 * j + 1]);
        *(u32x4*)&Bs[buf][nB][kg * 16]     = b0;
        *(u32x4*)&Bs[buf][nB][kg * 16 + 8] = b1;
    };

    // A direct: wave-private rows (each row used by exactly one wave).
    const ushort* arow = a + (size_t)(rowBase + wv * 16 + col) * D_ + quad * 8;
    uint4 apre[2];                       // [k32]
    auto load_a = [&](int kt) {
        apre[0] = *(const uint4*)(arow + kt * 64);
        apre[1] = *(const uint4*)(arow + kt * 64 + 32);
    };

    f32x4 acc[4];
#pragma unroll
    for (int j = 0; j < 4; j++) acc[j] = (f32x4){0.f, 0.f, 0.f, 0.f};

    load_a(0);
    load_b(0);
    stage_b(0);
    __syncthreads();

    const int NT = D_ / 64;              // 12
    int cur = 0;
    for (int kt = 0; kt < NT; kt++) {
        const bool more = (kt + 1 < NT);

        short8 af[2];
        af[0] = __builtin_bit_cast(short8, apre[0]);
        af[1] = __builtin_bit_cast(short8, apre[1]);

        if (more) { load_a(kt + 1); load_b(kt + 1); }

#pragma unroll
        for (int k32 = 0; k32 < 2; k32++) {
            short8 bf[4];
#pragma unroll
            for (int nt = 0; nt < 4; nt++)
                bf[nt] = *(const short8*)&Bs[cur][nt * 16 + col][k32 * 32 + quad * 8];
#pragma unroll
            for (int nt = 0; nt < 4; nt++)
                acc[nt] = __builtin_amdgcn_mfma_f32_16x16x32_bf16(af[k32], bf[nt], acc[nt], 0, 0, 0);
        }

        if (more) {
            stage_b(cur ^ 1);
            __syncthreads();
            cur ^= 1;
        }
    }

    float b2[4];
#pragma unroll
    for (int nt = 0; nt < 4; nt++) b2[nt] = bias[colBase + nt * 16 + col];
#pragma unroll
    for (int r = 0; r < 4; r++) {
        int m = rowBase + wv * 16 + quad * 4 + r;
        float* dst = out + (size_t)m * D_ + colBase;
#pragma unroll
        for (int nt = 0; nt < 4; nt++)
            dst[nt * 16 + col] = acc[nt][r] + b2[nt];
    }
}

// ---------------------------------------------------------------------------
extern "C" void kernel_launch(void* const* d_in, const int* in_sizes, int n_in,
                              void* d_out, int out_size, void* d_ws, size_t ws_size,
                              hipStream_t stream) {
    const float* x    = (const float*)d_in[0];
    const float* Wqkv = (const float*)d_in[1];
    const float* qs   = (const float*)d_in[2];
    const float* qb   = (const float*)d_in[3];
    const float* ks   = (const float*)d_in[4];
    const float* kb   = (const float*)d_in[5];
    const float* osc  = (const float*)d_in[6];
    const float* ob   = (const float*)d_in[7];
    const float* Wout = (const float*)d_in[8];
    const float* bout = (const float*)d_in[9];
    float* out = (float*)d_out;

    // Workspace: qkv bf16 18.9MB | (nsp-1) bf16 O-partials | nsp fp32 l-partials.
    ushort* qkv = (ushort*)d_ws;
    const size_t qkvE = (size_t)3 * B_ * H_ * P_ * HD_;
    const size_t oE   = (size_t)B_ * H_ * P_ * HD_;
    const size_t lE   = (size_t)B_ * H_ * P_;
    ushort* obase = qkv + qkvE;
    const size_t need4 = (qkvE + 3 * oE) * sizeof(ushort) + 4 * lE * sizeof(float);
    const int nsp = (ws_size >= need4) ? 4 : 2;
    ushort* op[4];
    float* lbase;
    if (nsp == 4) {
        op[0] = obase; op[1] = obase + oE; op[2] = obase + 2 * oE; op[3] = (ushort*)out;
        lbase = (float*)(obase + 3 * oE);
    } else {
        op[0] = obase; op[1] = (ushort*)out; op[2] = obase; op[3] = obase;
        lbase = (float*)(obase + oE);
    }
    float* lp[4] = {lbase, lbase + lE, lbase + 2 * lE, lbase + 3 * lE};
    ushort* ln_buf = qkv;   // overlays dead q-region after attention

    gemm_qkv_mfma<<<dim3((N1_ / 64) * (M_ / 128)), 256, 0, stream>>>(x, Wqkv, qs, qb, ks, kb, qkv);
    attn_split<<<dim3(P_ / 128, B_ * H_, nsp), 256, 0, stream>>>(
        qkv, op[0], op[1], op[2], op[3], lp[0], lp[1], lp[2], lp[3]);
    ln_o<<<dim3(M_), 256, 0, stream>>>(
        op[0], op[1], op[2], op[3], lp[0], lp[1], lp[2], lp[3], nsp, ln_buf, osc, ob);
    gemm_out_mfma<<<dim3((D_ / 64) * (M_ / 64)), 256, 0, stream>>>(ln_buf, Wout, bout, out);
}

// Round 10
// 206.958 us; speedup vs baseline: 1.0902x; 1.0902x over previous
//
#include <hip/hip_runtime.h>
#include <hip/hip_bf16.h>

// Problem constants (B=2, P=2048, D=768, H=12, hd=64)
#define B_  2
#define P_  2048
#define D_  768
#define H_  12
#define HD_ 64
#define M_  (B_ * P_)   // 4096
#define N1_ (3 * D_)    // 2304

typedef __attribute__((ext_vector_type(8))) short short8;    // 8 bf16 (4 VGPRs)
typedef __attribute__((ext_vector_type(4))) float f32x4;     // 16x16 MFMA acc
typedef __attribute__((ext_vector_type(16))) float f32x16;   // 32x32 MFMA acc
typedef __attribute__((ext_vector_type(4))) unsigned u32x4;
typedef unsigned short ushort;

__device__ __forceinline__ ushort f2bf(float f) {
    unsigned u = __float_as_uint(f);
    u += 0x7fffu + ((u >> 16) & 1u);   // RNE
    return (ushort)(u >> 16);
}

// Pack 2 floats -> 1 dword of 2x bf16 (lo=a, hi=b), RNE. HW-verified (r5/r6).
__device__ __forceinline__ unsigned cvtpk(float a, float b) {
    unsigned r;
    asm("v_cvt_pk_bf16_f32 %0, %1, %2" : "=v"(r) : "v"(a), "v"(b));
    return r;
}

__device__ __forceinline__ float bf2f(ushort u) {
    return __uint_as_float((unsigned)u << 16);
}

// Swap bits 2 and 3 of a slot index (involution) — attn K staging permutation.
__device__ __forceinline__ int swap23(int s) {
    return (s & ~12) | ((s & 4) << 1) | ((s & 8) >> 1);
}

// Q pre-scale: hd^-0.5 * log2(e) — attn uses exp2 directly.
#define QSC_ (0.125f * 1.44269504088896340736f)

// ===========================================================================
// Kernel 0 (R10): one-shot fp32 -> bf16 precast of x, W_qkv, W_out.
// Removes all conversion VALU from GEMM hot loops and halves their fetch.
// ===========================================================================
__global__ __launch_bounds__(256) void precast(const float* __restrict__ x,
                                               const float* __restrict__ wqkv,
                                               const float* __restrict__ wout,
                                               ushort* __restrict__ xb,
                                               ushort* __restrict__ wqb,
                                               ushort* __restrict__ wob) {
    const int stride = gridDim.x * 256;
    int tid = blockIdx.x * 256 + threadIdx.x;
    const int nx = M_ * D_ / 4, nq = D_ * N1_ / 4, no = D_ * D_ / 4;
    for (int i = tid; i < nx; i += stride) {
        float4 v = ((const float4*)x)[i];
        ((uint2*)xb)[i] = {cvtpk(v.x, v.y), cvtpk(v.z, v.w)};
    }
    for (int i = tid; i < nq; i += stride) {
        float4 v = ((const float4*)wqkv)[i];
        ((uint2*)wqb)[i] = {cvtpk(v.x, v.y), cvtpk(v.z, v.w)};
    }
    for (int i = tid; i < no; i += stride) {
        float4 v = ((const float4*)wout)[i];
        ((uint2*)wob)[i] = {cvtpk(v.x, v.y), cvtpk(v.z, v.w)};
    }
}

// ===========================================================================
// Kernel 1 (R10): qkv = x_bf16 @ Wqkv_bf16 + fused per-head QK-LayerNorm.
// R7 structure restored (best measured config): 128x128 tile, BK=32,
// 512 thr / 8 waves, SINGLE-buffered padded LDS (20.5KB -> 4 blocks/CU).
// bf16 inputs: A stage = one 16B load + one ds_write_b128 per thread;
// B stage = 8 coalesced 2B loads + one ds_write_b128. No in-loop cvt.
// ===========================================================================
__global__ __launch_bounds__(512) void gemm_qkv_mfma(
        const ushort* __restrict__ x, const ushort* __restrict__ w,
        const float* __restrict__ qs, const float* __restrict__ qb,
        const float* __restrict__ ks, const float* __restrict__ kb,
        ushort* __restrict__ qkv) {
    __shared__ __align__(16) ushort As[128][40];
    __shared__ __align__(16) ushort Bs[128][40];

    const int tid  = threadIdx.x;
    const int lane = tid & 63;
    const int wv   = tid >> 6;            // 0..7
    const int quad = lane >> 4;
    const int col  = lane & 15;
    const int wr   = (wv >> 1) * 32;
    const int wc   = (wv & 1) * 64;
    const int rowBase = blockIdx.y * 128;
    const int colBase = blockIdx.x * 128;

    const int amr = tid >> 2, ac4 = tid & 3;    // A: row 0..127, 16B chunk 0..3
    const int nB  = tid & 127, kq = tid >> 7;   // B: n 0..127, k-group 0..3

    uint4  apre;
    ushort bpre[8];
    auto load_tile = [&](int kt) {
        const int k0 = kt * 32;
        apre = *(const uint4*)(x + (size_t)(rowBase + amr) * D_ + k0 + ac4 * 8);
#pragma unroll
        for (int j = 0; j < 8; j++)
            bpre[j] = w[(size_t)(k0 + kq * 8 + j) * N1_ + colBase + nB];
    };

    f32x4 acc[2][4];
#pragma unroll
    for (int i = 0; i < 2; i++)
#pragma unroll
        for (int j = 0; j < 4; j++) acc[i][j] = (f32x4){0.f, 0.f, 0.f, 0.f};

    load_tile(0);
    const int NT = D_ / 32;
    for (int kt = 0; kt < NT; kt++) {
        __syncthreads();
        *(uint4*)&As[amr][ac4 * 8] = apre;
        *(short8*)&Bs[nB][kq * 8]  = *(short8*)&bpre[0];
        __syncthreads();
        if (kt + 1 < NT) load_tile(kt + 1);

        short8 af[2], bf[4];
#pragma unroll
        for (int mt = 0; mt < 2; mt++) af[mt] = *(const short8*)&As[wr + mt * 16 + col][quad * 8];
#pragma unroll
        for (int nt = 0; nt < 4; nt++) bf[nt] = *(const short8*)&Bs[wc + nt * 16 + col][quad * 8];
#pragma unroll
        for (int mt = 0; mt < 2; mt++)
#pragma unroll
            for (int nt = 0; nt < 4; nt++)
                acc[mt][nt] = __builtin_amdgcn_mfma_f32_16x16x32_bf16(af[mt], bf[nt], acc[mt][nt], 0, 0, 0);
    }

    const int comp = colBase / D_;
    const int rem  = colBase + wc - comp * D_;
    const int h    = rem >> 6;
    float sc4[4] = {0, 0, 0, 0}, bi4[4] = {0, 0, 0, 0};
    if (comp == 0) {
#pragma unroll
        for (int nt = 0; nt < 4; nt++) { sc4[nt] = qs[nt * 16 + col]; bi4[nt] = qb[nt * 16 + col]; }
    } else if (comp == 1) {
#pragma unroll
        for (int nt = 0; nt < 4; nt++) { sc4[nt] = ks[nt * 16 + col]; bi4[nt] = kb[nt * 16 + col]; }
    }

#pragma unroll
    for (int mt = 0; mt < 2; mt++) {
#pragma unroll
        for (int r = 0; r < 4; r++) {
            int m  = rowBase + wr + mt * 16 + quad * 4 + r;
            int bb = m >> 11;
            int p  = m & 2047;
            float v0 = acc[mt][0][r], v1 = acc[mt][1][r], v2 = acc[mt][2][r], v3 = acc[mt][3][r];
            if (comp < 2) {
                float s = v0 + v1 + v2 + v3;
#pragma unroll
                for (int off = 1; off < 16; off <<= 1) s += __shfl_xor(s, off, 64);
                float mean = s * (1.0f / 64.0f);
                float d0 = v0 - mean, d1 = v1 - mean, d2 = v2 - mean, d3 = v3 - mean;
                float sq = d0 * d0 + d1 * d1 + d2 * d2 + d3 * d3;
#pragma unroll
                for (int off = 1; off < 16; off <<= 1) sq += __shfl_xor(sq, off, 64);
                float inv = rsqrtf(sq * (1.0f / 64.0f) + 1e-6f);
                v0 = d0 * inv * sc4[0] + bi4[0];
                v1 = d1 * inv * sc4[1] + bi4[1];
                v2 = d2 * inv * sc4[2] + bi4[2];
                v3 = d3 * inv * sc4[3] + bi4[3];
                if (comp == 0) { v0 *= QSC_; v1 *= QSC_; v2 *= QSC_; v3 *= QSC_; }
            }
            size_t base = ((((size_t)comp * B_ + bb) * H_ + h) * P_ + p) * HD_;
            qkv[base +  0 + col] = f2bf(v0);
            qkv[base + 16 + col] = f2bf(v1);
            qkv[base + 32 + col] = f2bf(v2);
            qkv[base + 48 + col] = f2bf(v3);
        }
    }
}

// ===========================================================================
// Kernel 2: flash attention (unchanged from R8/R9 — swapped QK^T, swap23,
// double-buffered K/V, exp2 softmax, in-register P, bf16 partial-O).
// ===========================================================================
__global__ __launch_bounds__(256) void attn_split(const ushort* __restrict__ qkv,
                                                  ushort* __restrict__ o0, ushort* __restrict__ o1,
                                                  ushort* __restrict__ o2, ushort* __restrict__ o3,
                                                  float* __restrict__ l0, float* __restrict__ l1,
                                                  float* __restrict__ l2, float* __restrict__ l3) {
    const int p0  = blockIdx.x * 128;
    const int bh  = blockIdx.y;
    const int s   = blockIdx.z;
    const int nsp = gridDim.z;           // 2 or 4
    const int b   = bh / H_, h = bh % H_;
    ushort* opart = (s == 0) ? o0 : (s == 1) ? o1 : (s == 2) ? o2 : o3;
    float*  lpart = (s == 0) ? l0 : (s == 1) ? l1 : (s == 2) ? l2 : l3;
    const int tid  = threadIdx.x;
    const int lane = tid & 63;
    const int wv   = tid >> 6;
    const int half = lane >> 5;     // 0/1
    const int n32  = lane & 31;     // q-column of this lane

    __shared__ __align__(16) ushort KVs[2][2][64][72];

    const size_t hs  = (size_t)P_ * HD_;
    const int    kv0 = s * (P_ / nsp);
    const ushort* qg = qkv + ((size_t)(0 * B_ + b) * H_ + h) * hs + (size_t)(p0 + wv * 32) * HD_;
    const ushort* kg = qkv + ((size_t)(1 * B_ + b) * H_ + h) * hs + (size_t)kv0 * HD_;
    const ushort* vg = qkv + ((size_t)(2 * B_ + b) * H_ + h) * hs + (size_t)kv0 * HD_;

    short8 aq[4];
#pragma unroll
    for (int ks2 = 0; ks2 < 4; ks2++)
        aq[ks2] = *(const short8*)(qg + (size_t)n32 * HD_ + ks2 * 16 + half * 8);

    float lsum = 0.f;
    f32x16 oaccT[2];
#pragma unroll
    for (int nt = 0; nt < 2; nt++)
#pragma unroll
        for (int r = 0; r < 16; r++) oaccT[nt][r] = 0.f;

    const int kr = tid >> 3, kc8 = tid & 7;
    const int krs = swap23(kr);
    const int vd = tid & 63,  vkh = tid >> 6;

    uint4  kpre[2];
    ushort vpre[16];
    auto load_tile = [&](int kt) {
        const ushort* kg_t = kg + (size_t)kt * 64 * HD_;
        const ushort* vg_t = vg + (size_t)kt * 64 * HD_;
        kpre[0] = *(const uint4*)(kg_t + (size_t)kr * HD_ + kc8 * 8);
        kpre[1] = *(const uint4*)(kg_t + (size_t)(kr + 32) * HD_ + kc8 * 8);
#pragma unroll
        for (int j = 0; j < 16; j++)
            vpre[j] = vg_t[(size_t)(vkh * 16 + j) * HD_ + vd];
    };
    auto stage = [&](int buf) {
        *(uint4*)&KVs[buf][0][krs][kc8 * 8]      = kpre[0];
        *(uint4*)&KVs[buf][0][krs + 32][kc8 * 8] = kpre[1];
        *(short8*)&KVs[buf][1][vd][vkh * 16]     = *(short8*)&vpre[0];
        *(short8*)&KVs[buf][1][vd][vkh * 16 + 8] = *(short8*)&vpre[8];
    };

    load_tile(0);
    stage(0);
    __syncthreads();

    const int NT = (P_ / 64) / nsp;
    int cur = 0;
    for (int kt = 0; kt < NT; kt++) {
        const bool more = (kt + 1 < NT);
        if (more) load_tile(kt + 1);

        ushort (*Ks)[72] = KVs[cur][0];
        ushort (*Vs)[72] = KVs[cur][1];

#pragma unroll
        for (int nt = 0; nt < 2; nt++) {
            f32x16 sc;
#pragma unroll
            for (int r = 0; r < 16; r++) sc[r] = 0.f;
#pragma unroll
            for (int ks2 = 0; ks2 < 4; ks2++) {
                short8 kb2 = *(const short8*)&Ks[nt * 32 + n32][ks2 * 16 + half * 8];
                sc = __builtin_amdgcn_mfma_f32_32x32x16_bf16(kb2, aq[ks2], sc, 0, 0, 0);
            }
            float p[16];
#pragma unroll
            for (int r = 0; r < 16; r++) {
                p[r] = __builtin_amdgcn_exp2f(sc[r]);
                lsum += p[r];
            }
            unsigned w[8];
#pragma unroll
            for (int i = 0; i < 8; i++) w[i] = cvtpk(p[2 * i], p[2 * i + 1]);
#pragma unroll
            for (int kp2 = 0; kp2 < 2; kp2++) {
                u32x4 t = {w[kp2 * 4 + 0], w[kp2 * 4 + 1], w[kp2 * 4 + 2], w[kp2 * 4 + 3]};
                short8 pb = __builtin_bit_cast(short8, t);
                const int kstep = nt * 2 + kp2;
#pragma unroll
                for (int ntd = 0; ntd < 2; ntd++) {
                    short8 av = *(const short8*)&Vs[ntd * 32 + n32][kstep * 16 + half * 8];
                    oaccT[ntd] = __builtin_amdgcn_mfma_f32_32x32x16_bf16(av, pb, oaccT[ntd], 0, 0, 0);
                }
            }
        }

        if (more) {
            stage(cur ^ 1);
            __syncthreads();
            cur ^= 1;
        }
    }

    lsum += __shfl_xor(lsum, 32, 64);
    if (lane < 32)
        lpart[(size_t)bh * P_ + p0 + wv * 32 + lane] = lsum;

    float* scr = (float*)&KVs[0][0][0][0] + wv * 1152;
#pragma unroll
    for (int ntd = 0; ntd < 2; ntd++) {
#pragma unroll
        for (int r = 0; r < 16; r++)
            scr[n32 * 36 + (r & 3) + 8 * (r >> 2) + 4 * half] = oaccT[ntd][r];
#pragma unroll
        for (int i = 0; i < 4; i++) {
            int ql = i * 8 + (lane >> 3);
            int c4 = lane & 7;
            float4 v = *(const float4*)&scr[ql * 36 + c4 * 4];
            uint2 pk = {cvtpk(v.x, v.y), cvtpk(v.z, v.w)};
            *(uint2*)(opart + ((size_t)bh * P_ + p0 + wv * 32 + ql) * HD_ + ntd * 32 + c4 * 4) = pk;
        }
    }
}

// ===========================================================================
// Kernel 3: LayerNorm over D=768, fused split-combine of bf16 partials.
// (unchanged from R8/R9)
// ===========================================================================
__global__ __launch_bounds__(256) void ln_o(const ushort* __restrict__ o0,
                                            const ushort* __restrict__ o1,
                                            const ushort* __restrict__ o2,
                                            const ushort* __restrict__ o3,
                                            const float* __restrict__ l0,
                                            const float* __restrict__ l1,
                                            const float* __restrict__ l2,
                                            const float* __restrict__ l3,
                                            const int ns,
                                            ushort* __restrict__ lnb,
                                            const float* __restrict__ osc,
                                            const float* __restrict__ ob) {
    __shared__ float red[4];
    __shared__ float red2[4];
    const int row = blockIdx.x;          // b*P + p
    const int b   = row >> 11;
    const int p   = row & (P_ - 1);
    const int tid = threadIdx.x;

    auto src = [&](int d) {
        int h = d >> 6;
        size_t lr  = (size_t)(b * H_ + h) * P_ + p;
        size_t idx = lr * HD_ + (d & 63);
        float num = bf2f(o0[idx]) + bf2f(o1[idx]);
        float den = l0[lr] + l1[lr];
        if (ns == 4) { num += bf2f(o2[idx]) + bf2f(o3[idx]); den += l2[lr] + l3[lr]; }
        return num / den;
    };
    float v0 = src(tid);
    float v1 = src(tid + 256);
    float v2 = src(tid + 512);
    float s = v0 + v1 + v2;
#pragma unroll
    for (int o = 32; o > 0; o >>= 1) s += __shfl_xor(s, o, 64);
    if ((tid & 63) == 0) red[tid >> 6] = s;
    __syncthreads();
    float mean = (red[0] + red[1] + red[2] + red[3]) * (1.0f / 768.0f);
    float d0 = v0 - mean, d1 = v1 - mean, d2 = v2 - mean;
    float sq = d0 * d0 + d1 * d1 + d2 * d2;
#pragma unroll
    for (int o = 32; o > 0; o >>= 1) sq += __shfl_xor(sq, o, 64);
    if ((tid & 63) == 0) red2[tid >> 6] = sq;
    __syncthreads();
    float var = (red2[0] + red2[1] + red2[2] + red2[3]) * (1.0f / 768.0f);
    float inv = rsqrtf(var + 1e-6f);
    const size_t base = (size_t)row * D_;
    lnb[base + tid]       = f2bf(d0 * inv * osc[tid]       + ob[tid]);
    lnb[base + tid + 256] = f2bf(d1 * inv * osc[tid + 256] + ob[tid + 256]);
    lnb[base + tid + 512] = f2bf(d2 * inv * osc[tid + 512] + ob[tid + 512]);
}

// ===========================================================================
// Kernel 4 (R10): out = ln_buf(bf16) @ Wout_bf16 + b_out. R7 structure
// restored: 64x64 tile, BK=32, 256 thr, single-buffered padded LDS.
// ===========================================================================
__global__ __launch_bounds__(256) void gemm_out_mfma(
        const ushort* __restrict__ a, const ushort* __restrict__ w,
        const float* __restrict__ bias, float* __restrict__ out) {
    __shared__ __align__(16) ushort As[64][40];
    __shared__ __align__(16) ushort Bs[64][40];

    const int tid  = threadIdx.x;
    const int lane = tid & 63;
    const int wv   = tid >> 6;
    const int quad = lane >> 4;
    const int col  = lane & 15;
    const int wr   = (wv >> 1) * 32;
    const int wc   = (wv & 1) * 32;
    const int rowBase = blockIdx.y * 64;
    const int colBase = blockIdx.x * 64;

    const int am  = tid >> 2, ac8 = tid & 3;
    const int nB  = tid & 63, kq = tid >> 6;

    uint4  apre;
    ushort bpre[8];
    auto load_tile = [&](int kt) {
        const int k0 = kt * 32;
        apre = *(const uint4*)(a + (size_t)(rowBase + am) * D_ + k0 + ac8 * 8);
#pragma unroll
        for (int j = 0; j < 8; j++)
            bpre[j] = w[(size_t)(k0 + kq * 8 + j) * D_ + colBase + nB];
    };

    f32x4 acc[2][2];
#pragma unroll
    for (int i = 0; i < 2; i++)
#pragma unroll
        for (int j = 0; j < 2; j++) acc[i][j] = (f32x4){0.f, 0.f, 0.f, 0.f};

    load_tile(0);
    const int NT = D_ / 32;
    for (int kt = 0; kt < NT; kt++) {
        __syncthreads();
        *(uint4*)&As[am][ac8 * 8] = apre;
        *(short8*)&Bs[nB][kq * 8] = *(short8*)&bpre[0];
        __syncthreads();
        if (kt + 1 < NT) load_tile(kt + 1);

        short8 af[2], bf[2];
#pragma unroll
        for (int mt = 0; mt < 2; mt++) af[mt] = *(const short8*)&As[wr + mt * 16 + col][quad * 8];
#pragma unroll
        for (int nt = 0; nt < 2; nt++) bf[nt] = *(const short8*)&Bs[wc + nt * 16 + col][quad * 8];
#pragma unroll
        for (int mt = 0; mt < 2; mt++)
#pragma unroll
            for (int nt = 0; nt < 2; nt++)
                acc[mt][nt] = __builtin_amdgcn_mfma_f32_16x16x32_bf16(af[mt], bf[nt], acc[mt][nt], 0, 0, 0);
    }

    float b2[2];
#pragma unroll
    for (int nt = 0; nt < 2; nt++) b2[nt] = bias[colBase + wc + nt * 16 + col];
#pragma unroll
    for (int mt = 0; mt < 2; mt++) {
#pragma unroll
        for (int r = 0; r < 4; r++) {
            int m = rowBase + wr + mt * 16 + quad * 4 + r;
            float* dst = out + (size_t)m * D_ + colBase + wc;
#pragma unroll
            for (int nt = 0; nt < 2; nt++)
                dst[nt * 16 + col] = acc[mt][nt][r] + b2[nt];
        }
    }
}

// ---------------------------------------------------------------------------
extern "C" void kernel_launch(void* const* d_in, const int* in_sizes, int n_in,
                              void* d_out, int out_size, void* d_ws, size_t ws_size,
                              hipStream_t stream) {
    const float* x    = (const float*)d_in[0];
    const float* Wqkv = (const float*)d_in[1];
    const float* qs   = (const float*)d_in[2];
    const float* qb   = (const float*)d_in[3];
    const float* ks   = (const float*)d_in[4];
    const float* kb   = (const float*)d_in[5];
    const float* osc  = (const float*)d_in[6];
    const float* ob   = (const float*)d_in[7];
    const float* Wout = (const float*)d_in[8];
    const float* bout = (const float*)d_in[9];
    float* out = (float*)d_out;

    // Workspace: qkv bf16 18.9MB | (nsp-1) bf16 O-partials | nsp fp32 l |
    // bf16 casts of x (6.3MB), Wqkv (3.5MB), Wout (1.2MB).
    ushort* qkv = (ushort*)d_ws;
    const size_t qkvE  = (size_t)3 * B_ * H_ * P_ * HD_;
    const size_t oE    = (size_t)B_ * H_ * P_ * HD_;
    const size_t lE    = (size_t)B_ * H_ * P_;
    const size_t castE = (size_t)M_ * D_ + (size_t)D_ * N1_ + (size_t)D_ * D_;
    ushort* obase = qkv + qkvE;
    const size_t need4 = (qkvE + 3 * oE + castE) * sizeof(ushort) + 4 * lE * sizeof(float);
    const int nsp = (ws_size >= need4) ? 4 : 2;
    ushort* op[4];
    float* lbase;
    if (nsp == 4) {
        op[0] = obase; op[1] = obase + oE; op[2] = obase + 2 * oE; op[3] = (ushort*)out;
        lbase = (float*)(obase + 3 * oE);
    } else {
        op[0] = obase; op[1] = (ushort*)out; op[2] = obase; op[3] = obase;
        lbase = (float*)(obase + oE);
    }
    float* lp[4] = {lbase, lbase + lE, lbase + 2 * lE, lbase + 3 * lE};
    ushort* xb  = (ushort*)(lp[0] + 4 * lE);
    ushort* wqb = xb + (size_t)M_ * D_;
    ushort* wob = wqb + (size_t)D_ * N1_;
    ushort* ln_buf = qkv;   // overlays dead q-region after attention

    precast<<<dim3(1024), 256, 0, stream>>>(x, Wqkv, Wout, xb, wqb, wob);
    gemm_qkv_mfma<<<dim3(N1_ / 128, M_ / 128), 512, 0, stream>>>(xb, wqb, qs, qb, ks, kb, qkv);
    attn_split<<<dim3(P_ / 128, B_ * H_, nsp), 256, 0, stream>>>(
        qkv, op[0], op[1], op[2], op[3], lp[0], lp[1], lp[2], lp[3]);
    ln_o<<<dim3(M_), 256, 0, stream>>>(
        op[0], op[1], op[2], op[3], lp[0], lp[1], lp[2], lp[3], nsp, ln_buf, osc, ob);
    gemm_out_mfma<<<dim3(D_ / 64, M_ / 64), 256, 0, stream>>>(ln_buf, wob, bout, out);
}

// Round 11
// 204.875 us; speedup vs baseline: 1.1013x; 1.0102x over previous
//
#include <hip/hip_runtime.h>
#include <hip/hip_bf16.h>

// Problem constants (B=2, P=2048, D=768, H=12, hd=64)
#define B_  2
#define P_  2048
#define D_  768
#define H_  12
#define HD_ 64
#define M_  (B_ * P_)   // 4096
#define N1_ (3 * D_)    // 2304

typedef __attribute__((ext_vector_type(8))) short short8;    // 8 bf16 (4 VGPRs)
typedef __attribute__((ext_vector_type(4))) float f32x4;     // 16x16 MFMA acc
typedef __attribute__((ext_vector_type(16))) float f32x16;   // 32x32 MFMA acc
typedef __attribute__((ext_vector_type(4))) unsigned u32x4;
typedef unsigned short ushort;

__device__ __forceinline__ ushort f2bf(float f) {
    unsigned u = __float_as_uint(f);
    u += 0x7fffu + ((u >> 16) & 1u);   // RNE
    return (ushort)(u >> 16);
}

// Pack 2 floats -> 1 dword of 2x bf16 (lo=a, hi=b), RNE. HW-verified (r5/r6).
__device__ __forceinline__ unsigned cvtpk(float a, float b) {
    unsigned r;
    asm("v_cvt_pk_bf16_f32 %0, %1, %2" : "=v"(r) : "v"(a), "v"(b));
    return r;
}

__device__ __forceinline__ float bf2f(ushort u) {
    return __uint_as_float((unsigned)u << 16);
}

// Swap bits 2 and 3 of a slot index (involution) — attn K staging permutation.
__device__ __forceinline__ int swap23(int s) {
    return (s & ~12) | ((s & 4) << 1) | ((s & 8) >> 1);
}

// Q pre-scale: hd^-0.5 * log2(e) — attn uses exp2 directly.
#define QSC_ (0.125f * 1.44269504088896340736f)

// ===========================================================================
// Kernel 0: one-shot fp32 -> bf16 precast of x, W_qkv, W_out. (unchanged R10)
// ===========================================================================
__global__ __launch_bounds__(256) void precast(const float* __restrict__ x,
                                               const float* __restrict__ wqkv,
                                               const float* __restrict__ wout,
                                               ushort* __restrict__ xb,
                                               ushort* __restrict__ wqb,
                                               ushort* __restrict__ wob) {
    const int stride = gridDim.x * 256;
    int tid = blockIdx.x * 256 + threadIdx.x;
    const int nx = M_ * D_ / 4, nq = D_ * N1_ / 4, no = D_ * D_ / 4;
    for (int i = tid; i < nx; i += stride) {
        float4 v = ((const float4*)x)[i];
        ((uint2*)xb)[i] = {cvtpk(v.x, v.y), cvtpk(v.z, v.w)};
    }
    for (int i = tid; i < nq; i += stride) {
        float4 v = ((const float4*)wqkv)[i];
        ((uint2*)wqb)[i] = {cvtpk(v.x, v.y), cvtpk(v.z, v.w)};
    }
    for (int i = tid; i < no; i += stride) {
        float4 v = ((const float4*)wout)[i];
        ((uint2*)wob)[i] = {cvtpk(v.x, v.y), cvtpk(v.z, v.w)};
    }
}

// ===========================================================================
// Kernel 1: qkv = x_bf16 @ Wqkv_bf16 + fused per-head QK-LayerNorm.
// (unchanged R10: 128x128, BK=32, 512 thr, single-buffered padded LDS)
// ===========================================================================
__global__ __launch_bounds__(512) void gemm_qkv_mfma(
        const ushort* __restrict__ x, const ushort* __restrict__ w,
        const float* __restrict__ qs, const float* __restrict__ qb,
        const float* __restrict__ ks, const float* __restrict__ kb,
        ushort* __restrict__ qkv) {
    __shared__ __align__(16) ushort As[128][40];
    __shared__ __align__(16) ushort Bs[128][40];

    const int tid  = threadIdx.x;
    const int lane = tid & 63;
    const int wv   = tid >> 6;            // 0..7
    const int quad = lane >> 4;
    const int col  = lane & 15;
    const int wr   = (wv >> 1) * 32;
    const int wc   = (wv & 1) * 64;
    const int rowBase = blockIdx.y * 128;
    const int colBase = blockIdx.x * 128;

    const int amr = tid >> 2, ac4 = tid & 3;    // A: row 0..127, 16B chunk 0..3
    const int nB  = tid & 127, kq = tid >> 7;   // B: n 0..127, k-group 0..3

    uint4  apre;
    ushort bpre[8];
    auto load_tile = [&](int kt) {
        const int k0 = kt * 32;
        apre = *(const uint4*)(x + (size_t)(rowBase + amr) * D_ + k0 + ac4 * 8);
#pragma unroll
        for (int j = 0; j < 8; j++)
            bpre[j] = w[(size_t)(k0 + kq * 8 + j) * N1_ + colBase + nB];
    };

    f32x4 acc[2][4];
#pragma unroll
    for (int i = 0; i < 2; i++)
#pragma unroll
        for (int j = 0; j < 4; j++) acc[i][j] = (f32x4){0.f, 0.f, 0.f, 0.f};

    load_tile(0);
    const int NT = D_ / 32;
    for (int kt = 0; kt < NT; kt++) {
        __syncthreads();
        *(uint4*)&As[amr][ac4 * 8] = apre;
        *(short8*)&Bs[nB][kq * 8]  = *(short8*)&bpre[0];
        __syncthreads();
        if (kt + 1 < NT) load_tile(kt + 1);

        short8 af[2], bf[4];
#pragma unroll
        for (int mt = 0; mt < 2; mt++) af[mt] = *(const short8*)&As[wr + mt * 16 + col][quad * 8];
#pragma unroll
        for (int nt = 0; nt < 4; nt++) bf[nt] = *(const short8*)&Bs[wc + nt * 16 + col][quad * 8];
#pragma unroll
        for (int mt = 0; mt < 2; mt++)
#pragma unroll
            for (int nt = 0; nt < 4; nt++)
                acc[mt][nt] = __builtin_amdgcn_mfma_f32_16x16x32_bf16(af[mt], bf[nt], acc[mt][nt], 0, 0, 0);
    }

    const int comp = colBase / D_;
    const int rem  = colBase + wc - comp * D_;
    const int h    = rem >> 6;
    float sc4[4] = {0, 0, 0, 0}, bi4[4] = {0, 0, 0, 0};
    if (comp == 0) {
#pragma unroll
        for (int nt = 0; nt < 4; nt++) { sc4[nt] = qs[nt * 16 + col]; bi4[nt] = qb[nt * 16 + col]; }
    } else if (comp == 1) {
#pragma unroll
        for (int nt = 0; nt < 4; nt++) { sc4[nt] = ks[nt * 16 + col]; bi4[nt] = kb[nt * 16 + col]; }
    }

#pragma unroll
    for (int mt = 0; mt < 2; mt++) {
#pragma unroll
        for (int r = 0; r < 4; r++) {
            int m  = rowBase + wr + mt * 16 + quad * 4 + r;
            int bb = m >> 11;
            int p  = m & 2047;
            float v0 = acc[mt][0][r], v1 = acc[mt][1][r], v2 = acc[mt][2][r], v3 = acc[mt][3][r];
            if (comp < 2) {
                float s = v0 + v1 + v2 + v3;
#pragma unroll
                for (int off = 1; off < 16; off <<= 1) s += __shfl_xor(s, off, 64);
                float mean = s * (1.0f / 64.0f);
                float d0 = v0 - mean, d1 = v1 - mean, d2 = v2 - mean, d3 = v3 - mean;
                float sq = d0 * d0 + d1 * d1 + d2 * d2 + d3 * d3;
#pragma unroll
                for (int off = 1; off < 16; off <<= 1) sq += __shfl_xor(sq, off, 64);
                float inv = rsqrtf(sq * (1.0f / 64.0f) + 1e-6f);
                v0 = d0 * inv * sc4[0] + bi4[0];
                v1 = d1 * inv * sc4[1] + bi4[1];
                v2 = d2 * inv * sc4[2] + bi4[2];
                v3 = d3 * inv * sc4[3] + bi4[3];
                if (comp == 0) { v0 *= QSC_; v1 *= QSC_; v2 *= QSC_; v3 *= QSC_; }
            }
            size_t base = ((((size_t)comp * B_ + bb) * H_ + h) * P_ + p) * HD_;
            qkv[base +  0 + col] = f2bf(v0);
            qkv[base + 16 + col] = f2bf(v1);
            qkv[base + 32 + col] = f2bf(v2);
            qkv[base + 48 + col] = f2bf(v3);
        }
    }
}

// ===========================================================================
// Kernel 2 (R11): flash attention, 64 q per wave (two 32-q subtiles), block
// = 256 q rows. Swapped QK^T + swap23 staging + exp2 softmax + in-register
// P + bf16 partial-O — all fragment math identical to R7-R10 (verified).
// Per tile: 32 MFMA per wave (2x R10) over the same K/V staging; (nt,qsub)
// processed sequentially to bound transient registers. s_setprio(1) around
// MFMA clusters (guide m191: +4-7% attn).
// ===========================================================================
__global__ __launch_bounds__(256) void attn_split(const ushort* __restrict__ qkv,
                                                  ushort* __restrict__ o0, ushort* __restrict__ o1,
                                                  ushort* __restrict__ o2, ushort* __restrict__ o3,
                                                  float* __restrict__ l0, float* __restrict__ l1,
                                                  float* __restrict__ l2, float* __restrict__ l3) {
    const int p0  = blockIdx.x * 256;
    const int bh  = blockIdx.y;
    const int s   = blockIdx.z;
    const int nsp = gridDim.z;           // 2 or 4
    const int b   = bh / H_, h = bh % H_;
    ushort* opart = (s == 0) ? o0 : (s == 1) ? o1 : (s == 2) ? o2 : o3;
    float*  lpart = (s == 0) ? l0 : (s == 1) ? l1 : (s == 2) ? l2 : l3;
    const int tid  = threadIdx.x;
    const int lane = tid & 63;
    const int wv   = tid >> 6;
    const int half = lane >> 5;     // 0/1
    const int n32  = lane & 31;     // q-column of this lane

    __shared__ __align__(16) ushort KVs[2][2][64][72];

    const size_t hs  = (size_t)P_ * HD_;
    const int    kv0 = s * (P_ / nsp);
    const ushort* qg = qkv + ((size_t)(0 * B_ + b) * H_ + h) * hs + (size_t)(p0 + wv * 64) * HD_;
    const ushort* kg = qkv + ((size_t)(1 * B_ + b) * H_ + h) * hs + (size_t)kv0 * HD_;
    const ushort* vg = qkv + ((size_t)(2 * B_ + b) * H_ + h) * hs + (size_t)kv0 * HD_;

    // Q fragments for both subtiles: B[k=8*half+j][n=q=n32].
    short8 aq[2][4];
#pragma unroll
    for (int qs2 = 0; qs2 < 2; qs2++)
#pragma unroll
        for (int ks2 = 0; ks2 < 4; ks2++)
            aq[qs2][ks2] = *(const short8*)(qg + (size_t)(qs2 * 32 + n32) * HD_ + ks2 * 16 + half * 8);

    float lsum[2] = {0.f, 0.f};
    f32x16 oaccT[2][2];                  // [qsub][ntd]
#pragma unroll
    for (int q2 = 0; q2 < 2; q2++)
#pragma unroll
        for (int nt = 0; nt < 2; nt++)
#pragma unroll
            for (int r = 0; r < 16; r++) oaccT[q2][nt][r] = 0.f;

    const int kr = tid >> 3, kc8 = tid & 7;
    const int krs = swap23(kr);
    const int vd = tid & 63,  vkh = tid >> 6;

    uint4  kpre[2];
    ushort vpre[16];
    auto load_tile = [&](int kt) {
        const ushort* kg_t = kg + (size_t)kt * 64 * HD_;
        const ushort* vg_t = vg + (size_t)kt * 64 * HD_;
        kpre[0] = *(const uint4*)(kg_t + (size_t)kr * HD_ + kc8 * 8);
        kpre[1] = *(const uint4*)(kg_t + (size_t)(kr + 32) * HD_ + kc8 * 8);
#pragma unroll
        for (int j = 0; j < 16; j++)
            vpre[j] = vg_t[(size_t)(vkh * 16 + j) * HD_ + vd];
    };
    auto stage = [&](int buf) {
        *(uint4*)&KVs[buf][0][krs][kc8 * 8]      = kpre[0];
        *(uint4*)&KVs[buf][0][krs + 32][kc8 * 8] = kpre[1];
        *(short8*)&KVs[buf][1][vd][vkh * 16]     = *(short8*)&vpre[0];
        *(short8*)&KVs[buf][1][vd][vkh * 16 + 8] = *(short8*)&vpre[8];
    };

    load_tile(0);
    stage(0);
    __syncthreads();

    const int NT = (P_ / 64) / nsp;      // 8 (nsp=4) or 16 (nsp=2) — even
    int cur = 0;
    for (int kt = 0; kt < NT; kt++) {
        const bool more = (kt + 1 < NT);
        if (more) load_tile(kt + 1);

        ushort (*Ks)[72] = KVs[cur][0];
        ushort (*Vs)[72] = KVs[cur][1];

#pragma unroll
        for (int nt = 0; nt < 2; nt++) {
#pragma unroll
            for (int q2 = 0; q2 < 2; q2++) {
                f32x16 sc;
#pragma unroll
                for (int r = 0; r < 16; r++) sc[r] = 0.f;
                __builtin_amdgcn_s_setprio(1);
#pragma unroll
                for (int ks2 = 0; ks2 < 4; ks2++) {
                    short8 kb2 = *(const short8*)&Ks[nt * 32 + n32][ks2 * 16 + half * 8];
                    sc = __builtin_amdgcn_mfma_f32_32x32x16_bf16(kb2, aq[q2][ks2], sc, 0, 0, 0);
                }
                __builtin_amdgcn_s_setprio(0);
                float p[16];
#pragma unroll
                for (int r = 0; r < 16; r++) {
                    p[r] = __builtin_amdgcn_exp2f(sc[r]);
                    lsum[q2] += p[r];
                }
                unsigned w[8];
#pragma unroll
                for (int i = 0; i < 8; i++) w[i] = cvtpk(p[2 * i], p[2 * i + 1]);
                __builtin_amdgcn_s_setprio(1);
#pragma unroll
                for (int kp2 = 0; kp2 < 2; kp2++) {
                    u32x4 t = {w[kp2 * 4 + 0], w[kp2 * 4 + 1], w[kp2 * 4 + 2], w[kp2 * 4 + 3]};
                    short8 pb = __builtin_bit_cast(short8, t);
                    const int kstep = nt * 2 + kp2;
#pragma unroll
                    for (int ntd = 0; ntd < 2; ntd++) {
                        short8 av = *(const short8*)&Vs[ntd * 32 + n32][kstep * 16 + half * 8];
                        oaccT[q2][ntd] = __builtin_amdgcn_mfma_f32_32x32x16_bf16(av, pb, oaccT[q2][ntd], 0, 0, 0);
                    }
                }
                __builtin_amdgcn_s_setprio(0);
            }
        }

        if (more) {
            stage(cur ^ 1);
            __syncthreads();
            cur ^= 1;
        }
    }

    // Row-sums: lane-local + one cross-half exchange, per subtile.
#pragma unroll
    for (int q2 = 0; q2 < 2; q2++)
        lsum[q2] += __shfl_xor(lsum[q2], 32, 64);
    if (lane < 32) {
        lpart[(size_t)bh * P_ + p0 + wv * 64 +  0 + lane] = lsum[0];
        lpart[(size_t)bh * P_ + p0 + wv * 64 + 32 + lane] = lsum[1];
    }

    // O^T -> O transpose through buffer-0 LDS (per-wave 32x36 f32 scratch),
    // bf16-pack at the store; run per subtile. Buffer-0 safety: last tile
    // read buffer 1 (NT even); buffer-0 reads were ordered by the kt=NT-2
    // barrier. In-wave DS ordering covers scr write->read.
    float* scr = (float*)&KVs[0][0][0][0] + wv * 1152;
#pragma unroll
    for (int q2 = 0; q2 < 2; q2++) {
#pragma unroll
        for (int ntd = 0; ntd < 2; ntd++) {
#pragma unroll
            for (int r = 0; r < 16; r++)
                scr[n32 * 36 + (r & 3) + 8 * (r >> 2) + 4 * half] = oaccT[q2][ntd][r];
#pragma unroll
            for (int i = 0; i < 4; i++) {
                int ql = i * 8 + (lane >> 3);
                int c4 = lane & 7;
                float4 v = *(const float4*)&scr[ql * 36 + c4 * 4];
                uint2 pk = {cvtpk(v.x, v.y), cvtpk(v.z, v.w)};
                *(uint2*)(opart + ((size_t)bh * P_ + p0 + wv * 64 + q2 * 32 + ql) * HD_ + ntd * 32 + c4 * 4) = pk;
            }
        }
    }
}

// ===========================================================================
// Kernel 3: LayerNorm over D=768, fused split-combine of bf16 partials.
// (unchanged)
// ===========================================================================
__global__ __launch_bounds__(256) void ln_o(const ushort* __restrict__ o0,
                                            const ushort* __restrict__ o1,
                                            const ushort* __restrict__ o2,
                                            const ushort* __restrict__ o3,
                                            const float* __restrict__ l0,
                                            const float* __restrict__ l1,
                                            const float* __restrict__ l2,
                                            const float* __restrict__ l3,
                                            const int ns,
                                            ushort* __restrict__ lnb,
                                            const float* __restrict__ osc,
                                            const float* __restrict__ ob) {
    __shared__ float red[4];
    __shared__ float red2[4];
    const int row = blockIdx.x;          // b*P + p
    const int b   = row >> 11;
    const int p   = row & (P_ - 1);
    const int tid = threadIdx.x;

    auto src = [&](int d) {
        int h = d >> 6;
        size_t lr  = (size_t)(b * H_ + h) * P_ + p;
        size_t idx = lr * HD_ + (d & 63);
        float num = bf2f(o0[idx]) + bf2f(o1[idx]);
        float den = l0[lr] + l1[lr];
        if (ns == 4) { num += bf2f(o2[idx]) + bf2f(o3[idx]); den += l2[lr] + l3[lr]; }
        return num / den;
    };
    float v0 = src(tid);
    float v1 = src(tid + 256);
    float v2 = src(tid + 512);
    float s = v0 + v1 + v2;
#pragma unroll
    for (int o = 32; o > 0; o >>= 1) s += __shfl_xor(s, o, 64);
    if ((tid & 63) == 0) red[tid >> 6] = s;
    __syncthreads();
    float mean = (red[0] + red[1] + red[2] + red[3]) * (1.0f / 768.0f);
    float d0 = v0 - mean, d1 = v1 - mean, d2 = v2 - mean;
    float sq = d0 * d0 + d1 * d1 + d2 * d2;
#pragma unroll
    for (int o = 32; o > 0; o >>= 1) sq += __shfl_xor(sq, o, 64);
    if ((tid & 63) == 0) red2[tid >> 6] = sq;
    __syncthreads();
    float var = (red2[0] + red2[1] + red2[2] + red2[3]) * (1.0f / 768.0f);
    float inv = rsqrtf(var + 1e-6f);
    const size_t base = (size_t)row * D_;
    lnb[base + tid]       = f2bf(d0 * inv * osc[tid]       + ob[tid]);
    lnb[base + tid + 256] = f2bf(d1 * inv * osc[tid + 256] + ob[tid + 256]);
    lnb[base + tid + 512] = f2bf(d2 * inv * osc[tid + 512] + ob[tid + 512]);
}

// ===========================================================================
// Kernel 4: out = ln_buf(bf16) @ Wout_bf16 + b_out. (unchanged R10)
// ===========================================================================
__global__ __launch_bounds__(256) void gemm_out_mfma(
        const ushort* __restrict__ a, const ushort* __restrict__ w,
        const float* __restrict__ bias, float* __restrict__ out) {
    __shared__ __align__(16) ushort As[64][40];
    __shared__ __align__(16) ushort Bs[64][40];

    const int tid  = threadIdx.x;
    const int lane = tid & 63;
    const int wv   = tid >> 6;
    const int quad = lane >> 4;
    const int col  = lane & 15;
    const int wr   = (wv >> 1) * 32;
    const int wc   = (wv & 1) * 32;
    const int rowBase = blockIdx.y * 64;
    const int colBase = blockIdx.x * 64;

    const int am  = tid >> 2, ac8 = tid & 3;
    const int nB  = tid & 63, kq = tid >> 6;

    uint4  apre;
    ushort bpre[8];
    auto load_tile = [&](int kt) {
        const int k0 = kt * 32;
        apre = *(const uint4*)(a + (size_t)(rowBase + am) * D_ + k0 + ac8 * 8);
#pragma unroll
        for (int j = 0; j < 8; j++)
            bpre[j] = w[(size_t)(k0 + kq * 8 + j) * D_ + colBase + nB];
    };

    f32x4 acc[2][2];
#pragma unroll
    for (int i = 0; i < 2; i++)
#pragma unroll
        for (int j = 0; j < 2; j++) acc[i][j] = (f32x4){0.f, 0.f, 0.f, 0.f};

    load_tile(0);
    const int NT = D_ / 32;
    for (int kt = 0; kt < NT; kt++) {
        __syncthreads();
        *(uint4*)&As[am][ac8 * 8] = apre;
        *(short8*)&Bs[nB][kq * 8] = *(short8*)&bpre[0];
        __syncthreads();
        if (kt + 1 < NT) load_tile(kt + 1);

        short8 af[2], bf[2];
#pragma unroll
        for (int mt = 0; mt < 2; mt++) af[mt] = *(const short8*)&As[wr + mt * 16 + col][quad * 8];
#pragma unroll
        for (int nt = 0; nt < 2; nt++) bf[nt] = *(const short8*)&Bs[wc + nt * 16 + col][quad * 8];
#pragma unroll
        for (int mt = 0; mt < 2; mt++)
#pragma unroll
            for (int nt = 0; nt < 2; nt++)
                acc[mt][nt] = __builtin_amdgcn_mfma_f32_16x16x32_bf16(af[mt], bf[nt], acc[mt][nt], 0, 0, 0);
    }

    float b2[2];
#pragma unroll
    for (int nt = 0; nt < 2; nt++) b2[nt] = bias[colBase + wc + nt * 16 + col];
#pragma unroll
    for (int mt = 0; mt < 2; mt++) {
#pragma unroll
        for (int r = 0; r < 4; r++) {
            int m = rowBase + wr + mt * 16 + quad * 4 + r;
            float* dst = out + (size_t)m * D_ + colBase + wc;
#pragma unroll
            for (int nt = 0; nt < 2; nt++)
                dst[nt * 16 + col] = acc[mt][nt][r] + b2[nt];
        }
    }
}

// ---------------------------------------------------------------------------
extern "C" void kernel_launch(void* const* d_in, const int* in_sizes, int n_in,
                              void* d_out, int out_size, void* d_ws, size_t ws_size,
                              hipStream_t stream) {
    const float* x    = (const float*)d_in[0];
    const float* Wqkv = (const float*)d_in[1];
    const float* qs   = (const float*)d_in[2];
    const float* qb   = (const float*)d_in[3];
    const float* ks   = (const float*)d_in[4];
    const float* kb   = (const float*)d_in[5];
    const float* osc  = (const float*)d_in[6];
    const float* ob   = (const float*)d_in[7];
    const float* Wout = (const float*)d_in[8];
    const float* bout = (const float*)d_in[9];
    float* out = (float*)d_out;

    // Workspace: qkv bf16 18.9MB | (nsp-1) bf16 O-partials | nsp fp32 l |
    // bf16 casts of x (6.3MB), Wqkv (3.5MB), Wout (1.2MB).
    ushort* qkv = (ushort*)d_ws;
    const size_t qkvE  = (size_t)3 * B_ * H_ * P_ * HD_;
    const size_t oE    = (size_t)B_ * H_ * P_ * HD_;
    const size_t lE    = (size_t)B_ * H_ * P_;
    const size_t castE = (size_t)M_ * D_ + (size_t)D_ * N1_ + (size_t)D_ * D_;
    ushort* obase = qkv + qkvE;
    const size_t need4 = (qkvE + 3 * oE + castE) * sizeof(ushort) + 4 * lE * sizeof(float);
    const int nsp = (ws_size >= need4) ? 4 : 2;
    ushort* op[4];
    float* lbase;
    if (nsp == 4) {
        op[0] = obase; op[1] = obase + oE; op[2] = obase + 2 * oE; op[3] = (ushort*)out;
        lbase = (float*)(obase + 3 * oE);
    } else {
        op[0] = obase; op[1] = (ushort*)out; op[2] = obase; op[3] = obase;
        lbase = (float*)(obase + oE);
    }
    float* lp[4] = {lbase, lbase + lE, lbase + 2 * lE, lbase + 3 * lE};
    ushort* xb  = (ushort*)(lp[0] + 4 * lE);
    ushort* wqb = xb + (size_t)M_ * D_;
    ushort* wob = wqb + (size_t)D_ * N1_;
    ushort* ln_buf = qkv;   // overlays dead q-region after attention

    precast<<<dim3(1024), 256, 0, stream>>>(x, Wqkv, Wout, xb, wqb, wob);
    gemm_qkv_mfma<<<dim3(N1_ / 128, M_ / 128), 512, 0, stream>>>(xb, wqb, qs, qb, ks, kb, qkv);
    attn_split<<<dim3(P_ / 256, B_ * H_, nsp), 256, 0, stream>>>(
        qkv, op[0], op[1], op[2], op[3], lp[0], lp[1], lp[2], lp[3]);
    ln_o<<<dim3(M_), 256, 0, stream>>>(
        op[0], op[1], op[2], op[3], lp[0], lp[1], lp[2], lp[3], nsp, ln_buf, osc, ob);
    gemm_out_mfma<<<dim3(D_ / 64, M_ / 64), 256, 0, stream>>>(ln_buf, wob, bout, out);
}